// Round 18
// baseline (394.829 us; speedup 1.0000x reference)
//
#include <hip/hip_runtime.h>
#include <hip/hip_bf16.h>

#define NNODES 50000
#define NF 256
#define NH 4
#define NG 64
#define NCLS 10
#define MPAD 50048       // NNODES rounded up to multiple of 64
#define GEMM_BLKS (MPAD / 32)

typedef __hip_bfloat16 bf16;
typedef __attribute__((ext_vector_type(8))) short short8;
typedef __attribute__((ext_vector_type(4))) short bfx4;
typedef __attribute__((ext_vector_type(4))) float floatx4;

// flags[0] = indices are int64 ; flags[1] = floats are bf16
__device__ inline float ldf(const void* p, int i, int isbf) {
    return isbf ? __bfloat162float(((const bf16*)p)[i]) : ((const float*)p)[i];
}
__device__ inline float4 ld4f(const void* p, int i, int isbf) {
    if (isbf) {
        const unsigned* q = (const unsigned*)((const short*)p + i);
        unsigned u0 = q[0], u1 = q[1];
        return make_float4(__uint_as_float(u0 << 16), __uint_as_float(u0 & 0xFFFF0000u),
                           __uint_as_float(u1 << 16), __uint_as_float(u1 & 0xFFFF0000u));
    }
    return *(const float4*)((const float*)p + i);
}
__device__ inline void stf(void* p, int i, float v, int isbf) {
    if (isbf) ((bf16*)p)[i] = __float2bfloat16(v);
    else ((float*)p)[i] = v;
}
__device__ inline short f2bfbits(float v) {
    bf16 b = __float2bfloat16(v);
    return *reinterpret_cast<short*>(&b);
}
__device__ inline float bfbits2f(short s) {
    return __uint_as_float(((unsigned)(unsigned short)s) << 16);
}
__device__ inline unsigned char f2fp8(float v) {
    return (unsigned char)(__builtin_amdgcn_cvt_pk_fp8_f32(v, v, 0, false) & 0xFF);
}
__device__ inline int clampN(int v) { return ((unsigned)v < (unsigned)NNODES) ? v : 0; }
__device__ inline int clampG(int v) { return ((unsigned)v < (unsigned)NG) ? v : 0; }

__global__ void detect_kernel(const int* __restrict__ ei, const unsigned* __restrict__ w1,
                              int* __restrict__ flags) {
    __shared__ int nzOdd, insane;
    if (threadIdx.x == 0) { nzOdd = 0; insane = 0; }
    __syncthreads();
    if (ei[2 * threadIdx.x + 1] != 0) atomicAdd(&nzOdd, 1);
    unsigned lo = w1[threadIdx.x] & 0xFFFFu;
    unsigned ex = (lo >> 7) & 0xFFu;
    bool sane = ((lo & 0x7FFFu) == 0u) || (ex >= 90u && ex <= 133u);
    if (!sane) atomicAdd(&insane, 1);
    __syncthreads();
    if (threadIdx.x == 0) {
        flags[0] = (nzOdd == 0) ? 1 : 0;
        flags[1] = (insane == 0) ? 1 : 0;
    }
}

__device__ inline void edge_sd(const int* __restrict__ ei, int e, int E, int is64,
                               int& s_, int& d_) {
    if (e < E) {
        if (is64) { s_ = ei[2 * e]; d_ = ei[2 * E + 2 * e]; }
        else      { s_ = ei[e];     d_ = ei[E + e]; }
    } else {
        s_ = d_ = e - E;  // self-loop
    }
    s_ = clampN(s_);
    d_ = clampN(d_);
}

// ---- device bodies for fused kernels ---------------------------------------
__device__ __forceinline__ void repack_body(int b, const void* __restrict__ W,
                                            short* __restrict__ Bf, int isbf) {
    int i = b * 256 + threadIdx.x;  // 65536
    int j = i & 7, lane = (i >> 3) & 63, tile = i >> 9;
    int kt = tile >> 4, ctg = tile & 15;
    int k = kt * 32 + (lane >> 4) * 8 + j;
    int n = ctg * 16 + (lane & 15);
    Bf[i] = f2bfbits(ldf(W, k * NF + n, isbf));
}

__device__ __forceinline__ void deg_body(int b, const int* __restrict__ ei,
                                         int* __restrict__ deg, int E, int ET, int is64) {
    int e = b * 256 + threadIdx.x;
    if (e >= ET) return;
    int s_, d_;
    edge_sd(ei, e, E, is64, s_, d_);
    atomicAdd(&deg[d_], 1);
}

// prep: repack W1 (256 blocks) + repack W2 (256 blocks) + deg (rest)
__global__ __launch_bounds__(256) void prep_kernel(
        const void* __restrict__ W1, short* __restrict__ Bf1,
        const void* __restrict__ W2, short* __restrict__ Bf2,
        const int* __restrict__ ei, int* __restrict__ deg, int E, int ET,
        const int* __restrict__ flags) {
    int b = blockIdx.x;
    if (b < 256) repack_body(b, W1, Bf1, flags[1]);
    else if (b < 512) repack_body(b - 256, W2, Bf2, flags[1]);
    else deg_body(b - 512, ei, deg, E, ET, flags[0]);
}

__global__ void scan1_kernel(const int* __restrict__ deg, int* __restrict__ eprefix,
                             int* __restrict__ bsums, int n) {
    __shared__ int sc[256];
    int t = threadIdx.x, i = blockIdx.x * 256 + t;
    int val = (i < n) ? deg[i] : 0;
    sc[t] = val;
    __syncthreads();
    for (int off = 1; off < 256; off <<= 1) {
        int tmp = (t >= off) ? sc[t - off] : 0;
        __syncthreads();
        sc[t] += tmp;
        __syncthreads();
    }
    if (i < n) eprefix[i] = sc[t] - val;
    if (t == 255) bsums[blockIdx.x] = sc[255];
}

// scan2 + graph-boundary binary search (independent small jobs, one block)
__global__ void scan2_goff_kernel(const int* __restrict__ bsums, int* __restrict__ boffs, int nb,
                                  const int* __restrict__ bt, int* __restrict__ goff,
                                  int* __restrict__ gcnt, const int* __restrict__ flags) {
    __shared__ int sc[256];
    int t = threadIdx.x;
    int val = (t < nb) ? bsums[t] : 0;
    sc[t] = val;
    __syncthreads();
    for (int off = 1; off < 256; off <<= 1) {
        int tmp = (t >= off) ? sc[t - off] : 0;
        __syncthreads();
        sc[t] += tmp;
        __syncthreads();
    }
    if (t < nb) boffs[t] = sc[t] - val;
    // goff via binary search (batch sorted)
    int is64 = flags[0];
    if (t <= NG) {
        int lo = 0, hi = NNODES;
        while (lo < hi) {
            int mid = (lo + hi) >> 1;
            int b = clampG(is64 ? bt[2 * mid] : bt[mid]);
            if (b < t) lo = mid + 1; else hi = mid;
        }
        goff[t] = lo;
    }
    __syncthreads();
    if (t < NG) gcnt[t] = goff[t + 1] - goff[t];
}

__global__ void scan3_kernel(const int* __restrict__ eprefix, const int* __restrict__ boffs,
                             int* __restrict__ rowptr, int n, int ET) {
    int i = blockIdx.x * 256 + threadIdx.x;
    if (i < n) rowptr[i] = eprefix[i] + boffs[blockIdx.x];
    if (i == n) rowptr[n] = ET;
}

__device__ __forceinline__ void scatter_body(int b, const int* __restrict__ ei,
                                             const int* __restrict__ rowptr,
                                             int* __restrict__ cursor, int* __restrict__ srcs,
                                             int E, int ET, int is64) {
    int e = b * 256 + threadIdx.x;
    if (e >= ET) return;
    int s_, d_;
    edge_sd(ei, e, E, is64, s_, d_);
    int pos = atomicAdd(&cursor[d_], 1);
    srcs[rowptr[d_] + pos] = s_;
}

// ====== MFMA GEMM body + fused attention-logit epilogue ======================
// C8[M,256] fp8 = fp8(A @ B); a_src/a_dst from fp32 acc. A staged through LDS
// with contiguous 1KB global reads. applyBN: BN affine (from raw stats)
// computed into LDS and applied during bf16 staging.
__device__ __forceinline__ void gemm_body(
        int bid, const void* __restrict__ A, const short* __restrict__ Bf,
        unsigned char* __restrict__ C8, int M, const int* __restrict__ flags, int aFollows,
        const void* __restrict__ att_s, const void* __restrict__ att_d,
        float* __restrict__ a_src, float* __restrict__ a_dst,
        const float* __restrict__ bnsum, const float* __restrict__ bnsq,
        const void* __restrict__ gamma, const void* __restrict__ beta, int applyBN) {
    __shared__ short smem[16 * 528];  // 16 row-pairs x (512+16) shorts
    __shared__ float sscale[NF];
    __shared__ float sshift[NF];
    int isbf = flags[1];
    int aIsBf = aFollows ? isbf : 1;
    int t = threadIdx.x;
    int wave = t >> 6;
    int lane = t & 63;
    int am = lane & 15, aq = lane >> 4;
    int row0 = bid * 32;

    if (applyBN) {
        const float invN = 1.0f / (float)NNODES;
        float mu = bnsum[t] * invN;
        float var = fmaxf(bnsq[t] * invN - mu * mu, 0.f);
        float s = ldf(gamma, t, isbf) * rsqrtf(var + 1e-5f);
        sscale[t] = s;
        sshift[t] = ldf(beta, t, isbf) - mu * s;
        __syncthreads();
    }

    // ---- stage A tile (32 rows x 512B) into LDS ----
    if (aIsBf) {
        #pragma unroll
        for (int i = 0; i < 4; i++) {
            int j = wave * 4 + i;
            int grow = min(row0 + 2 * j + (lane >> 5), M - 1);
            int f0 = (lane & 31) * 8;
            short8 v = *(const short8*)((const short*)A + grow * NF + f0);
            if (applyBN) {
                #pragma unroll
                for (int jj = 0; jj < 8; jj++)
                    v[jj] = f2bfbits(bfbits2f(v[jj]) * sscale[f0 + jj] + sshift[f0 + jj]);
            }
            *(short8*)&smem[j * 528 + (lane >> 5) * 256 + f0] = v;
        }
    } else {
        #pragma unroll
        for (int i = 0; i < 4; i++) {
            int u = t * 4 + i;
            int row = u >> 5;
            int pos = u & 31;
            int grow = min(row0 + row, M - 1);
            const float* fp = (const float*)A + grow * NF + pos * 8;
            float4 f0 = *(const float4*)fp;
            float4 f1 = *(const float4*)(fp + 4);
            short8 v;
            v[0] = f2bfbits(f0.x); v[1] = f2bfbits(f0.y);
            v[2] = f2bfbits(f0.z); v[3] = f2bfbits(f0.w);
            v[4] = f2bfbits(f1.x); v[5] = f2bfbits(f1.y);
            v[6] = f2bfbits(f1.z); v[7] = f2bfbits(f1.w);
            *(short8*)&smem[(row >> 1) * 528 + (row & 1) * 256 + pos * 8] = v;
        }
    }
    __syncthreads();

    floatx4 acc[2][4];
    #pragma unroll
    for (int i = 0; i < 2; i++)
        #pragma unroll
        for (int j = 0; j < 4; j++) acc[i][j] = (floatx4){0.f, 0.f, 0.f, 0.f};

    int aoff0 = (am >> 1) * 528 + (am & 1) * 256 + aq * 8;
    #pragma unroll
    for (int kt = 0; kt < 8; kt++) {
        short8 a0 = *(const short8*)&smem[aoff0 + kt * 32];
        short8 a1 = *(const short8*)&smem[aoff0 + 8 * 528 + kt * 32];
        short8 b[4];
        #pragma unroll
        for (int ct = 0; ct < 4; ct++)
            b[ct] = *(const short8*)&Bf[((kt * 16 + wave * 4 + ct) * 64 + lane) * 8];
        #pragma unroll
        for (int ct = 0; ct < 4; ct++) {
            acc[0][ct] = __builtin_amdgcn_mfma_f32_16x16x32_bf16(a0, b[ct], acc[0][ct], 0, 0, 0);
            acc[1][ct] = __builtin_amdgcn_mfma_f32_16x16x32_bf16(a1, b[ct], acc[1][ct], 0, 0, 0);
        }
    }

    int rbase = aq * 4;
    int cbase = wave * 64 + am;
    #pragma unroll
    for (int rt = 0; rt < 2; rt++) {
        #pragma unroll
        for (int r = 0; r < 4; r++) {
            int row = row0 + rt * 16 + rbase + r;
            if (row < M) {
                #pragma unroll
                for (int ct = 0; ct < 4; ct++)
                    C8[row * NF + cbase + ct * 16] = f2fp8(acc[rt][ct][r]);
            }
        }
    }
    float attS[4], attD[4];
    #pragma unroll
    for (int ct = 0; ct < 4; ct++) {
        int col = wave * 64 + ct * 16 + am;
        attS[ct] = ldf(att_s, col, isbf);
        attD[ct] = ldf(att_d, col, isbf);
    }
    #pragma unroll
    for (int rt = 0; rt < 2; rt++) {
        #pragma unroll
        for (int r = 0; r < 4; r++) {
            float ps = 0.f, pd = 0.f;
            #pragma unroll
            for (int ct = 0; ct < 4; ct++) {
                float v = acc[rt][ct][r];
                ps += v * attS[ct];
                pd += v * attD[ct];
            }
            #pragma unroll
            for (int m = 1; m <= 8; m <<= 1) {
                ps += __shfl_xor(ps, m, 64);
                pd += __shfl_xor(pd, m, 64);
            }
            int row = row0 + rt * 16 + rbase + r;
            if (am == 0 && row < M) {
                a_src[row * NH + wave] = ps;
                a_dst[row * NH + wave] = pd;
            }
        }
    }
}

// gemm-1 fused with edge scatter (independent; different pipes, co-resident)
__global__ __launch_bounds__(256) void scatter_gemm1_kernel(
        const int* __restrict__ ei, const int* __restrict__ rowptr,
        int* __restrict__ cursor, int* __restrict__ srcs, int E, int ET,
        const void* __restrict__ A, const short* __restrict__ Bf,
        unsigned char* __restrict__ C8, int M,
        const void* __restrict__ att_s, const void* __restrict__ att_d,
        float* __restrict__ a_src, float* __restrict__ a_dst,
        const int* __restrict__ flags) {
    if (blockIdx.x < GEMM_BLKS)
        gemm_body(blockIdx.x, A, Bf, C8, M, flags, 1, att_s, att_d, a_src, a_dst,
                  nullptr, nullptr, nullptr, nullptr, 0);
    else
        scatter_body(blockIdx.x - GEMM_BLKS, ei, rowptr, cursor, srcs, E, ET, flags[0]);
}

// gemm-2 standalone (with fused BN affine from raw stats)
__global__ __launch_bounds__(256) void gemm2_kernel(
        const void* __restrict__ A, const short* __restrict__ Bf,
        unsigned char* __restrict__ C8, int M,
        const void* __restrict__ att_s, const void* __restrict__ att_d,
        float* __restrict__ a_src, float* __restrict__ a_dst,
        const float* __restrict__ bnsum, const float* __restrict__ bnsq,
        const void* __restrict__ gamma, const void* __restrict__ beta,
        const int* __restrict__ flags) {
    gemm_body(blockIdx.x, A, Bf, C8, M, flags, 0, att_s, att_d, a_src, a_dst,
              bnsum, bnsq, gamma, beta, 1);
}

__device__ inline float leaky_clamp(float v) {
    v = v > 0.f ? v : 0.2f * v;
    return fminf(fmaxf(v, -30.f), 30.f);
}

// ---- single-pass per-dst softmax-aggregate + bias + ELU + residual ---------
// out = (sum exp(e_k) h_k)/(sum exp(e_k)); e clamped +-30 (no overflow, den>0).
// ONE WAVE per dst; lane l owns features {4l..4l+3}; head hh = l>>4.
// applyBN: residual passes through BN affine computed from raw stats.
__global__ __launch_bounds__(64) void agg_csr_kernel(
        const int* __restrict__ rowptr, const int* __restrict__ srcs,
        const float* __restrict__ asrc, const float* __restrict__ adst,
        const unsigned char* __restrict__ h8, const void* __restrict__ bias,
        const void* __restrict__ resid, bf16* __restrict__ agg,
        const int* __restrict__ flags, int residFollows,
        const float* __restrict__ bnsum, const float* __restrict__ bnsq,
        const void* __restrict__ gamma, const void* __restrict__ beta, int applyBN) {
    int d = blockIdx.x;
    int l = threadIdx.x;
    int hh = l >> 4;
    int e16 = l & 15;
    int isbf = flags[1];
    int rIsBf = residFollows ? isbf : 1;
    int f0 = 4 * l;
    // per-lane BN affine coefficients for my 4 features
    float sc[4] = {1.f, 1.f, 1.f, 1.f}, sh[4] = {0.f, 0.f, 0.f, 0.f};
    if (applyBN) {
        const float invN = 1.0f / (float)NNODES;
        #pragma unroll
        for (int j = 0; j < 4; j++) {
            int f = f0 + j;
            float mu = bnsum[f] * invN;
            float var = fmaxf(bnsq[f] * invN - mu * mu, 0.f);
            float s = ldf(gamma, f, isbf) * rsqrtf(var + 1e-5f);
            sc[j] = s;
            sh[j] = ldf(beta, f, isbf) - mu * s;
        }
    }
    int beg = rowptr[d], end = rowptr[d + 1];
    float ad = adst[d * NH + hh];
    __shared__ float sAl[NH][16];
    __shared__ int sSrc[16];
    float a0 = 0.f, a1 = 0.f, a2 = 0.f, a3 = 0.f, den = 0.f;
    for (int cb = beg; cb < end; cb += 16) {
        int nk = min(16, end - cb);
        if (e16 < nk) {
            int s = srcs[cb + e16];
            if (hh == 0) sSrc[e16] = s;
            sAl[hh][e16] = __expf(leaky_clamp(asrc[s * NH + hh] + ad));
        }
        __syncthreads();
        for (int k = 0; k < nk; k++) {
            float al = sAl[hh][k];
            den += al;
            unsigned u = *(const unsigned*)&h8[sSrc[k] * NF + f0];
            auto lo = __builtin_amdgcn_cvt_pk_f32_fp8((int)u, false);
            auto hi = __builtin_amdgcn_cvt_pk_f32_fp8((int)u, true);
            a0 += al * lo[0];
            a1 += al * lo[1];
            a2 += al * hi[0];
            a3 += al * hi[1];
        }
        __syncthreads();
    }
    float inv = 1.f / fmaxf(den, 1e-30f);
    a0 *= inv; a1 *= inv; a2 *= inv; a3 *= inv;
    float4 r = ld4f(resid, d * NF + f0, rIsBf);
    if (applyBN) {
        r.x = r.x * sc[0] + sh[0];
        r.y = r.y * sc[1] + sh[1];
        r.z = r.z * sc[2] + sh[2];
        r.w = r.w * sc[3] + sh[3];
    }
    float v0 = a0 + ldf(bias, f0, isbf);
    float v1 = a1 + ldf(bias, f0 + 1, isbf);
    float v2 = a2 + ldf(bias, f0 + 2, isbf);
    float v3 = a3 + ldf(bias, f0 + 3, isbf);
    v0 = v0 > 0.f ? v0 : (__expf(v0) - 1.0f);
    v1 = v1 > 0.f ? v1 : (__expf(v1) - 1.0f);
    v2 = v2 > 0.f ? v2 : (__expf(v2) - 1.0f);
    v3 = v3 > 0.f ? v3 : (__expf(v3) - 1.0f);
    bfx4 o;
    o[0] = f2bfbits(v0 + r.x);
    o[1] = f2bfbits(v1 + r.y);
    o[2] = f2bfbits(v2 + r.z);
    o[3] = f2bfbits(v3 + r.w);
    *(bfx4*)&agg[d * NF + f0] = o;
}

// bn_stats body: 16B/thread loads + LDS reduce; nblocks = stats grid size
__device__ __forceinline__ void bn_stats_body(int b, int nblocks, const bf16* __restrict__ x,
                                              float* __restrict__ bsum, float* __restrict__ bsumsq) {
    __shared__ float ssum[8][256];
    __shared__ float ssq[8][256];
    int t = threadIdx.x;
    int fg = t & 31, rg = t >> 5;
    int f0 = fg * 8;
    float s[8] = {0, 0, 0, 0, 0, 0, 0, 0};
    float q[8] = {0, 0, 0, 0, 0, 0, 0, 0};
    for (int r = b * 8 + rg; r < NNODES; r += nblocks * 8) {
        short8 v = *(const short8*)&x[r * NF + f0];
        #pragma unroll
        for (int j = 0; j < 8; j++) {
            float fv = bfbits2f(v[j]);
            s[j] += fv;
            q[j] += fv * fv;
        }
    }
    #pragma unroll
    for (int j = 0; j < 8; j++) {
        ssum[rg][f0 + j] = s[j];
        ssq[rg][f0 + j] = q[j];
    }
    __syncthreads();
    float ts = 0.f, tq = 0.f;
    #pragma unroll
    for (int g = 0; g < 8; g++) {
        ts += ssum[g][t];
        tq += ssq[g][t];
    }
    atomicAdd(&bsum[t], ts);
    atomicAdd(&bsumsq[t], tq);
}

__global__ __launch_bounds__(256) void bn_stats_kernel(
        const bf16* __restrict__ x, float* __restrict__ bsum, float* __restrict__ bsumsq) {
    bn_stats_body(blockIdx.x, 512, x, bsum, bsumsq);
}

__device__ __forceinline__ void pool2_body(int b, const bf16* __restrict__ x,
                                           const int* __restrict__ goff, float* __restrict__ pooled) {
    int g = b >> 3, c = b & 7, t = threadIdx.x;
    int beg = goff[g], end = goff[g + 1];
    int len = end - beg;
    if (len <= 0) return;
    int chunk = (len + 7) >> 3;
    int s0 = beg + c * chunk;
    int s1 = min(s0 + chunk, end);
    if (s0 >= s1) return;
    float acc = 0.f;
    for (int n = s0; n < s1; n++) acc += __bfloat162float(x[n * NF + t]);
    atomicAdd(&pooled[g * NF + t], acc);
}

// bn_stats-2 fused with pooling (both read aggb, independent of each other)
__global__ __launch_bounds__(256) void stats_pool_kernel(
        const bf16* __restrict__ x, float* __restrict__ bsum, float* __restrict__ bsumsq,
        const int* __restrict__ goff, float* __restrict__ pooled) {
    if (blockIdx.x < 512) bn_stats_body(blockIdx.x, 512, x, bsum, bsumsq);
    else pool2_body(blockIdx.x - 512, x, goff, pooled);
}

// head: BN affine on pooled means (BN commutes with mean-pool) + MLP + lsm.
__global__ __launch_bounds__(256) void head_kernel(
        const float* __restrict__ pooled, const int* __restrict__ gcnt,
        const float* __restrict__ bnsum2, const float* __restrict__ bnsq2,
        const void* __restrict__ gamma2, const void* __restrict__ beta2,
        const void* __restrict__ fc1w, const void* __restrict__ fc1b,
        const void* __restrict__ fc2w, const void* __restrict__ fc2b,
        void* __restrict__ out, const int* __restrict__ flags) {
    int g = blockIdx.x;
    int t = threadIdx.x;
    int isbf = flags[1];
    __shared__ float p[NF];
    __shared__ float zpart[4][64];
    __shared__ float z[64];
    __shared__ float logits[NCLS];
    __shared__ float lse;
    float c = fmaxf((float)gcnt[g], 1.f);
    float invc = 1.f / c;
    const float invN = 1.0f / (float)NNODES;
    {
        float mu = bnsum2[t] * invN;
        float var = fmaxf(bnsq2[t] * invN - mu * mu, 0.f);
        float pm = pooled[g * NF + t] * invc;
        p[t] = ldf(gamma2, t, isbf) * ((pm - mu) * rsqrtf(var + 1e-5f)) + ldf(beta2, t, isbf);
    }
    __syncthreads();
    int o = t & 63, q = t >> 6;
    int k0 = q * 64;
    float acc = 0.f;
    if (isbf) {
        const bf16* w = (const bf16*)fc1w;
        #pragma unroll 8
        for (int k = k0; k < k0 + 64; k++) acc += p[k] * __bfloat162float(w[k * 64 + o]);
    } else {
        const float* w = (const float*)fc1w;
        #pragma unroll 8
        for (int k = k0; k < k0 + 64; k++) acc += p[k] * w[k * 64 + o];
    }
    zpart[q][o] = acc;
    __syncthreads();
    if (t < 64) {
        float v = zpart[0][t] + zpart[1][t] + zpart[2][t] + zpart[3][t] + ldf(fc1b, t, isbf);
        z[t] = v > 0.f ? v : 0.f;
    }
    __syncthreads();
    if (t < NCLS) {
        float a2 = ldf(fc2b, t, isbf);
        #pragma unroll 8
        for (int k = 0; k < 64; k++) a2 += z[k] * ldf(fc2w, k * NCLS + t, isbf);
        logits[t] = a2;
    }
    __syncthreads();
    if (t == 0) {
        float mx = logits[0];
        for (int j = 1; j < NCLS; j++) mx = fmaxf(mx, logits[j]);
        float se = 0.f;
        for (int j = 0; j < NCLS; j++) se += expf(logits[j] - mx);
        lse = mx + logf(se);
    }
    __syncthreads();
    if (t < NCLS) stf(out, g * NCLS + t, logits[t] - lse, isbf);
}

extern "C" void kernel_launch(void* const* d_in, const int* in_sizes, int n_in,
                              void* d_out, int out_size, void* d_ws, size_t ws_size,
                              hipStream_t stream) {
    const void* x = d_in[0];
    const int* edge_index = (const int*)d_in[1];
    const int* batch = (const int*)d_in[2];
    const void* W1 = d_in[3];
    const void* att_src1 = d_in[4];
    const void* att_dst1 = d_in[5];
    const void* b1 = d_in[6];
    const void* gamma1 = d_in[7];
    const void* beta1 = d_in[8];
    const void* W2 = d_in[9];
    const void* att_src2 = d_in[10];
    const void* att_dst2 = d_in[11];
    const void* b2 = d_in[12];
    const void* gamma2 = d_in[13];
    const void* beta2 = d_in[14];
    const void* fc1w = d_in[15];
    const void* fc1b = d_in[16];
    const void* fc2w = d_in[17];
    const void* fc2b = d_in[18];

    const int E = in_sizes[1] / 2;     // 400000
    const int ET = E + NNODES;         // + self-loops
    const int NE = NNODES * NF;
    const int NNH = NNODES * NH;
    const int NB = (NNODES + 255) / 256;
    const int NB1 = (NNODES + 1 + 255) / 256;
    const int NBE = (ET + 255) / 256;  // edge blocks

    // ---- workspace layout ----
    float* ws = (float*)d_ws;
    bf16* aggb = (bf16*)ws;                // N*256 bf16
    float* asrc = ws + NE / 2;             // N*4 (aliases scan scratch early)
    float* adst = asrc + NNH;              // N*4
    int* flags = (int*)(adst + NNH);       // 16
    unsigned char* h8 = (unsigned char*)(flags + 16);  // MPAD*256 fp8
    bf16* l1ob = (bf16*)(h8 + (size_t)MPAD * NF);      // (dead, layout keep)
    int* rowptr = (int*)(l1ob + (size_t)MPAD * NF);    // N+1 (+pad)
    int* srcs = rowptr + NNODES + 16;      // ET
    int* goff = srcs + ET + 16;            // NG+1
    // zero region (single memset): deg, cursor, gcnt, pooled, bnstat
    int* deg = goff + NG + 1 + 14;
    int* cursor = deg + NNODES;
    int* gcnt = cursor + NNODES;
    float* pooled = (float*)(gcnt + NG);   // 64*256
    float* bnstat = pooled + NG * NF;      // 4*256
    size_t zero_bytes = (size_t)(2 * NNODES + NG) * 4 + (size_t)(NG * NF + 4 * NF) * 4;
    short* Bf1 = (short*)(bnstat + 4 * NF);  // 65536 (outside zero region)
    short* Bf2 = Bf1 + NF * NF;              // 65536
    // scan scratch aliased onto asrc/adst (overwritten later by gemm epilogue)
    int* eprefix = (int*)asrc;
    int* bsums = eprefix + NNODES + 16;
    int* boffs = bsums + 256;

    float* bnsum1 = bnstat;
    float* bnsq1 = bnstat + NF;
    float* bnsum2 = bnstat + 2 * NF;
    float* bnsq2 = bnstat + 3 * NF;

    detect_kernel<<<1, 256, 0, stream>>>(edge_index, (const unsigned*)W1, flags);
    (void)hipMemsetAsync(deg, 0, zero_bytes, stream);

    // repack W1 + repack W2 + deg histogram, one dispatch
    prep_kernel<<<512 + NBE, 256, 0, stream>>>(W1, Bf1, W2, Bf2, edge_index, deg, E, ET, flags);
    scan1_kernel<<<NB, 256, 0, stream>>>(deg, eprefix, bsums, NNODES);
    scan2_goff_kernel<<<1, 256, 0, stream>>>(bsums, boffs, NB, batch, goff, gcnt, flags);
    scan3_kernel<<<NB1, 256, 0, stream>>>(eprefix, boffs, rowptr, NNODES, ET);

    // ================= layer 1 (gemm fused with edge scatter) ===============
    scatter_gemm1_kernel<<<GEMM_BLKS + NBE, 256, 0, stream>>>(
        edge_index, rowptr, cursor, srcs, E, ET,
        x, Bf1, h8, NNODES, att_src1, att_dst1, asrc, adst, flags);
    agg_csr_kernel<<<NNODES, 64, 0, stream>>>(rowptr, srcs, asrc, adst, h8, b1, x, aggb,
                                              flags, 1, nullptr, nullptr, nullptr, nullptr, 0);
    bn_stats_kernel<<<512, 256, 0, stream>>>(aggb, bnsum1, bnsq1);

    // ================= layer 2 (BN-1 affine fused from raw stats) ===========
    gemm2_kernel<<<GEMM_BLKS, 256, 0, stream>>>(aggb, Bf2, h8, NNODES,
                                                att_src2, att_dst2, asrc, adst,
                                                bnsum1, bnsq1, gamma1, beta1, flags);
    agg_csr_kernel<<<NNODES, 64, 0, stream>>>(rowptr, srcs, asrc, adst, h8, b2, aggb, aggb,
                                              flags, 0, bnsum1, bnsq1, gamma1, beta1, 1);

    // ================= stats-2 + pool (fused) + head ========================
    stats_pool_kernel<<<512 + NG * 8, 256, 0, stream>>>(aggb, bnsum2, bnsq2, goff, pooled);
    head_kernel<<<NG, 256, 0, stream>>>(pooled, gcnt, bnsum2, bnsq2, gamma2, beta2,
                                        fc1w, fc1b, fc2w, fc2b, d_out, flags);
}

// Round 19
// 364.815 us; speedup vs baseline: 1.0823x; 1.0823x over previous
//
#include <hip/hip_runtime.h>
#include <hip/hip_bf16.h>

#define NNODES 50000
#define NF 256
#define NH 4
#define NG 64
#define NCLS 10
#define MPAD 50048       // NNODES rounded up to multiple of 64
#define GEMM_BLKS (MPAD / 32)

typedef __hip_bfloat16 bf16;
typedef __attribute__((ext_vector_type(8))) short short8;
typedef __attribute__((ext_vector_type(4))) short bfx4;
typedef __attribute__((ext_vector_type(4))) float floatx4;

// flags[0] = indices are int64 ; flags[1] = floats are bf16
__device__ inline float ldf(const void* p, int i, int isbf) {
    return isbf ? __bfloat162float(((const bf16*)p)[i]) : ((const float*)p)[i];
}
__device__ inline float4 ld4f(const void* p, int i, int isbf) {
    if (isbf) {
        const unsigned* q = (const unsigned*)((const short*)p + i);
        unsigned u0 = q[0], u1 = q[1];
        return make_float4(__uint_as_float(u0 << 16), __uint_as_float(u0 & 0xFFFF0000u),
                           __uint_as_float(u1 << 16), __uint_as_float(u1 & 0xFFFF0000u));
    }
    return *(const float4*)((const float*)p + i);
}
__device__ inline void stf(void* p, int i, float v, int isbf) {
    if (isbf) ((bf16*)p)[i] = __float2bfloat16(v);
    else ((float*)p)[i] = v;
}
__device__ inline short f2bfbits(float v) {
    bf16 b = __float2bfloat16(v);
    return *reinterpret_cast<short*>(&b);
}
__device__ inline float bfbits2f(short s) {
    return __uint_as_float(((unsigned)(unsigned short)s) << 16);
}
__device__ inline unsigned char f2fp8(float v) {
    return (unsigned char)(__builtin_amdgcn_cvt_pk_fp8_f32(v, v, 0, false) & 0xFF);
}
__device__ inline int clampN(int v) { return ((unsigned)v < (unsigned)NNODES) ? v : 0; }
__device__ inline int clampG(int v) { return ((unsigned)v < (unsigned)NG) ? v : 0; }

__global__ void detect_kernel(const int* __restrict__ ei, const unsigned* __restrict__ w1,
                              int* __restrict__ flags) {
    __shared__ int nzOdd, insane;
    if (threadIdx.x == 0) { nzOdd = 0; insane = 0; }
    __syncthreads();
    if (ei[2 * threadIdx.x + 1] != 0) atomicAdd(&nzOdd, 1);
    unsigned lo = w1[threadIdx.x] & 0xFFFFu;
    unsigned ex = (lo >> 7) & 0xFFu;
    bool sane = ((lo & 0x7FFFu) == 0u) || (ex >= 90u && ex <= 133u);
    if (!sane) atomicAdd(&insane, 1);
    __syncthreads();
    if (threadIdx.x == 0) {
        flags[0] = (nzOdd == 0) ? 1 : 0;
        flags[1] = (insane == 0) ? 1 : 0;
    }
}

__device__ inline void edge_sd(const int* __restrict__ ei, int e, int E, int is64,
                               int& s_, int& d_) {
    if (e < E) {
        if (is64) { s_ = ei[2 * e]; d_ = ei[2 * E + 2 * e]; }
        else      { s_ = ei[e];     d_ = ei[E + e]; }
    } else {
        s_ = d_ = e - E;  // self-loop
    }
    s_ = clampN(s_);
    d_ = clampN(d_);
}

// ---- device bodies for fused kernels ---------------------------------------
__device__ __forceinline__ void repack_body(int b, const void* __restrict__ W,
                                            short* __restrict__ Bf, int isbf) {
    int i = b * 256 + threadIdx.x;  // 65536
    int j = i & 7, lane = (i >> 3) & 63, tile = i >> 9;
    int kt = tile >> 4, ctg = tile & 15;
    int k = kt * 32 + (lane >> 4) * 8 + j;
    int n = ctg * 16 + (lane & 15);
    Bf[i] = f2bfbits(ldf(W, k * NF + n, isbf));
}

__device__ __forceinline__ void deg_body(int b, const int* __restrict__ ei,
                                         int* __restrict__ deg, int E, int ET, int is64) {
    int e = b * 256 + threadIdx.x;
    if (e >= ET) return;
    int s_, d_;
    edge_sd(ei, e, E, is64, s_, d_);
    atomicAdd(&deg[d_], 1);
}

// prep: repack W1 (256 blocks) + repack W2 (256 blocks) + deg (rest)
__global__ __launch_bounds__(256) void prep_kernel(
        const void* __restrict__ W1, short* __restrict__ Bf1,
        const void* __restrict__ W2, short* __restrict__ Bf2,
        const int* __restrict__ ei, int* __restrict__ deg, int E, int ET,
        const int* __restrict__ flags) {
    int b = blockIdx.x;
    if (b < 256) repack_body(b, W1, Bf1, flags[1]);
    else if (b < 512) repack_body(b - 256, W2, Bf2, flags[1]);
    else deg_body(b - 512, ei, deg, E, ET, flags[0]);
}

__global__ void scan1_kernel(const int* __restrict__ deg, int* __restrict__ eprefix,
                             int* __restrict__ bsums, int n) {
    __shared__ int sc[256];
    int t = threadIdx.x, i = blockIdx.x * 256 + t;
    int val = (i < n) ? deg[i] : 0;
    sc[t] = val;
    __syncthreads();
    for (int off = 1; off < 256; off <<= 1) {
        int tmp = (t >= off) ? sc[t - off] : 0;
        __syncthreads();
        sc[t] += tmp;
        __syncthreads();
    }
    if (i < n) eprefix[i] = sc[t] - val;
    if (t == 255) bsums[blockIdx.x] = sc[255];
}

// scan2 + graph-boundary binary search (independent small jobs, one block)
__global__ void scan2_goff_kernel(const int* __restrict__ bsums, int* __restrict__ boffs, int nb,
                                  const int* __restrict__ bt, int* __restrict__ goff,
                                  int* __restrict__ gcnt, const int* __restrict__ flags) {
    __shared__ int sc[256];
    int t = threadIdx.x;
    int val = (t < nb) ? bsums[t] : 0;
    sc[t] = val;
    __syncthreads();
    for (int off = 1; off < 256; off <<= 1) {
        int tmp = (t >= off) ? sc[t - off] : 0;
        __syncthreads();
        sc[t] += tmp;
        __syncthreads();
    }
    if (t < nb) boffs[t] = sc[t] - val;
    int is64 = flags[0];
    if (t <= NG) {
        int lo = 0, hi = NNODES;
        while (lo < hi) {
            int mid = (lo + hi) >> 1;
            int b = clampG(is64 ? bt[2 * mid] : bt[mid]);
            if (b < t) lo = mid + 1; else hi = mid;
        }
        goff[t] = lo;
    }
    __syncthreads();
    if (t < NG) gcnt[t] = goff[t + 1] - goff[t];
}

__global__ void scan3_kernel(const int* __restrict__ eprefix, const int* __restrict__ boffs,
                             int* __restrict__ rowptr, int n, int ET) {
    int i = blockIdx.x * 256 + threadIdx.x;
    if (i < n) rowptr[i] = eprefix[i] + boffs[blockIdx.x];
    if (i == n) rowptr[n] = ET;
}

__device__ __forceinline__ void scatter_body(int b, const int* __restrict__ ei,
                                             const int* __restrict__ rowptr,
                                             int* __restrict__ cursor, int* __restrict__ srcs,
                                             int E, int ET, int is64) {
    int e = b * 256 + threadIdx.x;
    if (e >= ET) return;
    int s_, d_;
    edge_sd(ei, e, E, is64, s_, d_);
    int pos = atomicAdd(&cursor[d_], 1);
    srcs[rowptr[d_] + pos] = s_;
}

// BN affine coefficients: scale = gamma*rsqrt(var+eps), shift = beta - mu*scale
__global__ void bn_finalize_kernel(const float* __restrict__ bsum, const float* __restrict__ bsumsq,
                                   const void* __restrict__ gamma, const void* __restrict__ beta,
                                   float* __restrict__ scale, float* __restrict__ shift,
                                   const int* __restrict__ flags) {
    int t = threadIdx.x;  // 256
    int isbf = flags[1];
    const float invN = 1.0f / (float)NNODES;
    float mu = bsum[t] * invN;
    float var = fmaxf(bsumsq[t] * invN - mu * mu, 0.f);
    float s = ldf(gamma, t, isbf) * rsqrtf(var + 1e-5f);
    scale[t] = s;
    shift[t] = ldf(beta, t, isbf) - mu * s;
}

// ====== MFMA GEMM body + fused attention-logit epilogue ======================
// C8[M,256] fp8 = fp8(A @ B); a_src/a_dst from fp32 acc. A staged through LDS
// with contiguous 1KB global reads; optional precomputed per-feature affine
// (scaleA/shiftA) applied during bf16 staging.
__device__ __forceinline__ void gemm_body(
        int bid, const void* __restrict__ A, const short* __restrict__ Bf,
        unsigned char* __restrict__ C8, int M, const int* __restrict__ flags, int aFollows,
        const void* __restrict__ att_s, const void* __restrict__ att_d,
        float* __restrict__ a_src, float* __restrict__ a_dst,
        const float* __restrict__ scaleA, const float* __restrict__ shiftA) {
    __shared__ short smem[16 * 528];  // 16 row-pairs x (512+16) shorts
    int isbf = flags[1];
    int aIsBf = aFollows ? isbf : 1;
    int t = threadIdx.x;
    int wave = t >> 6;
    int lane = t & 63;
    int am = lane & 15, aq = lane >> 4;
    int row0 = bid * 32;

    // ---- stage A tile (32 rows x 512B) into LDS ----
    if (aIsBf) {
        #pragma unroll
        for (int i = 0; i < 4; i++) {
            int j = wave * 4 + i;
            int grow = min(row0 + 2 * j + (lane >> 5), M - 1);
            int f0 = (lane & 31) * 8;
            short8 v = *(const short8*)((const short*)A + grow * NF + f0);
            if (scaleA) {  // fused precomputed BN affine (layer 2)
                #pragma unroll
                for (int jj = 0; jj < 8; jj++)
                    v[jj] = f2bfbits(bfbits2f(v[jj]) * scaleA[f0 + jj] + shiftA[f0 + jj]);
            }
            *(short8*)&smem[j * 528 + (lane >> 5) * 256 + f0] = v;
        }
    } else {
        #pragma unroll
        for (int i = 0; i < 4; i++) {
            int u = t * 4 + i;
            int row = u >> 5;
            int pos = u & 31;
            int grow = min(row0 + row, M - 1);
            const float* fp = (const float*)A + grow * NF + pos * 8;
            float4 f0 = *(const float4*)fp;
            float4 f1 = *(const float4*)(fp + 4);
            short8 v;
            v[0] = f2bfbits(f0.x); v[1] = f2bfbits(f0.y);
            v[2] = f2bfbits(f0.z); v[3] = f2bfbits(f0.w);
            v[4] = f2bfbits(f1.x); v[5] = f2bfbits(f1.y);
            v[6] = f2bfbits(f1.z); v[7] = f2bfbits(f1.w);
            *(short8*)&smem[(row >> 1) * 528 + (row & 1) * 256 + pos * 8] = v;
        }
    }
    __syncthreads();

    floatx4 acc[2][4];
    #pragma unroll
    for (int i = 0; i < 2; i++)
        #pragma unroll
        for (int j = 0; j < 4; j++) acc[i][j] = (floatx4){0.f, 0.f, 0.f, 0.f};

    int aoff0 = (am >> 1) * 528 + (am & 1) * 256 + aq * 8;
    #pragma unroll
    for (int kt = 0; kt < 8; kt++) {
        short8 a0 = *(const short8*)&smem[aoff0 + kt * 32];
        short8 a1 = *(const short8*)&smem[aoff0 + 8 * 528 + kt * 32];
        short8 b[4];
        #pragma unroll
        for (int ct = 0; ct < 4; ct++)
            b[ct] = *(const short8*)&Bf[((kt * 16 + wave * 4 + ct) * 64 + lane) * 8];
        #pragma unroll
        for (int ct = 0; ct < 4; ct++) {
            acc[0][ct] = __builtin_amdgcn_mfma_f32_16x16x32_bf16(a0, b[ct], acc[0][ct], 0, 0, 0);
            acc[1][ct] = __builtin_amdgcn_mfma_f32_16x16x32_bf16(a1, b[ct], acc[1][ct], 0, 0, 0);
        }
    }

    int rbase = aq * 4;
    int cbase = wave * 64 + am;
    #pragma unroll
    for (int rt = 0; rt < 2; rt++) {
        #pragma unroll
        for (int r = 0; r < 4; r++) {
            int row = row0 + rt * 16 + rbase + r;
            if (row < M) {
                #pragma unroll
                for (int ct = 0; ct < 4; ct++)
                    C8[row * NF + cbase + ct * 16] = f2fp8(acc[rt][ct][r]);
            }
        }
    }
    float attS[4], attD[4];
    #pragma unroll
    for (int ct = 0; ct < 4; ct++) {
        int col = wave * 64 + ct * 16 + am;
        attS[ct] = ldf(att_s, col, isbf);
        attD[ct] = ldf(att_d, col, isbf);
    }
    #pragma unroll
    for (int rt = 0; rt < 2; rt++) {
        #pragma unroll
        for (int r = 0; r < 4; r++) {
            float ps = 0.f, pd = 0.f;
            #pragma unroll
            for (int ct = 0; ct < 4; ct++) {
                float v = acc[rt][ct][r];
                ps += v * attS[ct];
                pd += v * attD[ct];
            }
            #pragma unroll
            for (int m = 1; m <= 8; m <<= 1) {
                ps += __shfl_xor(ps, m, 64);
                pd += __shfl_xor(pd, m, 64);
            }
            int row = row0 + rt * 16 + rbase + r;
            if (am == 0 && row < M) {
                a_src[row * NH + wave] = ps;
                a_dst[row * NH + wave] = pd;
            }
        }
    }
}

// gemm-1 fused with edge scatter (independent; different pipes, co-resident)
__global__ __launch_bounds__(256) void scatter_gemm1_kernel(
        const int* __restrict__ ei, const int* __restrict__ rowptr,
        int* __restrict__ cursor, int* __restrict__ srcs, int E, int ET,
        const void* __restrict__ A, const short* __restrict__ Bf,
        unsigned char* __restrict__ C8, int M,
        const void* __restrict__ att_s, const void* __restrict__ att_d,
        float* __restrict__ a_src, float* __restrict__ a_dst,
        const int* __restrict__ flags) {
    if (blockIdx.x < GEMM_BLKS)
        gemm_body(blockIdx.x, A, Bf, C8, M, flags, 1, att_s, att_d, a_src, a_dst,
                  nullptr, nullptr);
    else
        scatter_body(blockIdx.x - GEMM_BLKS, ei, rowptr, cursor, srcs, E, ET, flags[0]);
}

// gemm-2 standalone (with fused precomputed BN affine)
__global__ __launch_bounds__(256) void gemm2_kernel(
        const void* __restrict__ A, const short* __restrict__ Bf,
        unsigned char* __restrict__ C8, int M,
        const void* __restrict__ att_s, const void* __restrict__ att_d,
        float* __restrict__ a_src, float* __restrict__ a_dst,
        const float* __restrict__ scaleA, const float* __restrict__ shiftA,
        const int* __restrict__ flags) {
    gemm_body(blockIdx.x, A, Bf, C8, M, flags, 0, att_s, att_d, a_src, a_dst,
              scaleA, shiftA);
}

__device__ inline float leaky_clamp(float v) {
    v = v > 0.f ? v : 0.2f * v;
    return fminf(fmaxf(v, -30.f), 30.f);
}

// ---- single-pass per-dst softmax-aggregate + bias + ELU + residual ---------
// out = (sum exp(e_k) h_k)/(sum exp(e_k)); e clamped +-30. ONE WAVE per dst;
// lane l owns features {4l..4l+3}; head hh = l>>4. rscale/rshift: precomputed
// BN affine applied to the residual (layer 2).
__global__ __launch_bounds__(64) void agg_csr_kernel(
        const int* __restrict__ rowptr, const int* __restrict__ srcs,
        const float* __restrict__ asrc, const float* __restrict__ adst,
        const unsigned char* __restrict__ h8, const void* __restrict__ bias,
        const void* __restrict__ resid, bf16* __restrict__ agg,
        const int* __restrict__ flags, int residFollows,
        const float* __restrict__ rscale, const float* __restrict__ rshift) {
    int d = blockIdx.x;
    int l = threadIdx.x;
    int hh = l >> 4;
    int e16 = l & 15;
    int isbf = flags[1];
    int rIsBf = residFollows ? isbf : 1;
    int beg = rowptr[d], end = rowptr[d + 1];
    float ad = adst[d * NH + hh];
    __shared__ float sAl[NH][16];
    __shared__ int sSrc[16];
    float a0 = 0.f, a1 = 0.f, a2 = 0.f, a3 = 0.f, den = 0.f;
    for (int cb = beg; cb < end; cb += 16) {
        int nk = min(16, end - cb);
        if (e16 < nk) {
            int s = srcs[cb + e16];
            if (hh == 0) sSrc[e16] = s;
            sAl[hh][e16] = __expf(leaky_clamp(asrc[s * NH + hh] + ad));
        }
        __syncthreads();
        for (int k = 0; k < nk; k++) {
            float al = sAl[hh][k];
            den += al;
            unsigned u = *(const unsigned*)&h8[sSrc[k] * NF + 4 * l];
            auto lo = __builtin_amdgcn_cvt_pk_f32_fp8((int)u, false);
            auto hi = __builtin_amdgcn_cvt_pk_f32_fp8((int)u, true);
            a0 += al * lo[0];
            a1 += al * lo[1];
            a2 += al * hi[0];
            a3 += al * hi[1];
        }
        __syncthreads();
    }
    float inv = 1.f / fmaxf(den, 1e-30f);
    a0 *= inv; a1 *= inv; a2 *= inv; a3 *= inv;
    int f0 = 4 * l;
    float4 r = ld4f(resid, d * NF + f0, rIsBf);
    if (rscale) {
        r.x = r.x * rscale[f0] + rshift[f0];
        r.y = r.y * rscale[f0 + 1] + rshift[f0 + 1];
        r.z = r.z * rscale[f0 + 2] + rshift[f0 + 2];
        r.w = r.w * rscale[f0 + 3] + rshift[f0 + 3];
    }
    float v0 = a0 + ldf(bias, f0, isbf);
    float v1 = a1 + ldf(bias, f0 + 1, isbf);
    float v2 = a2 + ldf(bias, f0 + 2, isbf);
    float v3 = a3 + ldf(bias, f0 + 3, isbf);
    v0 = v0 > 0.f ? v0 : (__expf(v0) - 1.0f);
    v1 = v1 > 0.f ? v1 : (__expf(v1) - 1.0f);
    v2 = v2 > 0.f ? v2 : (__expf(v2) - 1.0f);
    v3 = v3 > 0.f ? v3 : (__expf(v3) - 1.0f);
    bfx4 o;
    o[0] = f2bfbits(v0 + r.x);
    o[1] = f2bfbits(v1 + r.y);
    o[2] = f2bfbits(v2 + r.z);
    o[3] = f2bfbits(v3 + r.w);
    *(bfx4*)&agg[d * NF + f0] = o;
}

// bn_stats body: 16B/thread loads + LDS reduce
__device__ __forceinline__ void bn_stats_body(int b, int nblocks, const bf16* __restrict__ x,
                                              float* __restrict__ bsum, float* __restrict__ bsumsq) {
    __shared__ float ssum[8][256];
    __shared__ float ssq[8][256];
    int t = threadIdx.x;
    int fg = t & 31, rg = t >> 5;
    int f0 = fg * 8;
    float s[8] = {0, 0, 0, 0, 0, 0, 0, 0};
    float q[8] = {0, 0, 0, 0, 0, 0, 0, 0};
    for (int r = b * 8 + rg; r < NNODES; r += nblocks * 8) {
        short8 v = *(const short8*)&x[r * NF + f0];
        #pragma unroll
        for (int j = 0; j < 8; j++) {
            float fv = bfbits2f(v[j]);
            s[j] += fv;
            q[j] += fv * fv;
        }
    }
    #pragma unroll
    for (int j = 0; j < 8; j++) {
        ssum[rg][f0 + j] = s[j];
        ssq[rg][f0 + j] = q[j];
    }
    __syncthreads();
    float ts = 0.f, tq = 0.f;
    #pragma unroll
    for (int g = 0; g < 8; g++) {
        ts += ssum[g][t];
        tq += ssq[g][t];
    }
    atomicAdd(&bsum[t], ts);
    atomicAdd(&bsumsq[t], tq);
}

__global__ __launch_bounds__(256) void bn_stats_kernel(
        const bf16* __restrict__ x, float* __restrict__ bsum, float* __restrict__ bsumsq) {
    bn_stats_body(blockIdx.x, 512, x, bsum, bsumsq);
}

__device__ __forceinline__ void pool2_body(int b, const bf16* __restrict__ x,
                                           const int* __restrict__ goff, float* __restrict__ pooled) {
    int g = b >> 3, c = b & 7, t = threadIdx.x;
    int beg = goff[g], end = goff[g + 1];
    int len = end - beg;
    if (len <= 0) return;
    int chunk = (len + 7) >> 3;
    int s0 = beg + c * chunk;
    int s1 = min(s0 + chunk, end);
    if (s0 >= s1) return;
    float acc = 0.f;
    for (int n = s0; n < s1; n++) acc += __bfloat162float(x[n * NF + t]);
    atomicAdd(&pooled[g * NF + t], acc);
}

// bn_stats-2 fused with pooling (both read aggb, independent of each other)
__global__ __launch_bounds__(256) void stats_pool_kernel(
        const bf16* __restrict__ x, float* __restrict__ bsum, float* __restrict__ bsumsq,
        const int* __restrict__ goff, float* __restrict__ pooled) {
    if (blockIdx.x < 512) bn_stats_body(blockIdx.x, 512, x, bsum, bsumsq);
    else pool2_body(blockIdx.x - 512, x, goff, pooled);
}

// head: BN affine on pooled means (BN commutes with mean-pool) + MLP + lsm.
__global__ __launch_bounds__(256) void head_kernel(
        const float* __restrict__ pooled, const int* __restrict__ gcnt,
        const float* __restrict__ bnsum2, const float* __restrict__ bnsq2,
        const void* __restrict__ gamma2, const void* __restrict__ beta2,
        const void* __restrict__ fc1w, const void* __restrict__ fc1b,
        const void* __restrict__ fc2w, const void* __restrict__ fc2b,
        void* __restrict__ out, const int* __restrict__ flags) {
    int g = blockIdx.x;
    int t = threadIdx.x;
    int isbf = flags[1];
    __shared__ float p[NF];
    __shared__ float zpart[4][64];
    __shared__ float z[64];
    __shared__ float logits[NCLS];
    __shared__ float lse;
    float c = fmaxf((float)gcnt[g], 1.f);
    float invc = 1.f / c;
    const float invN = 1.0f / (float)NNODES;
    {
        float mu = bnsum2[t] * invN;
        float var = fmaxf(bnsq2[t] * invN - mu * mu, 0.f);
        float pm = pooled[g * NF + t] * invc;
        p[t] = ldf(gamma2, t, isbf) * ((pm - mu) * rsqrtf(var + 1e-5f)) + ldf(beta2, t, isbf);
    }
    __syncthreads();
    int o = t & 63, q = t >> 6;
    int k0 = q * 64;
    float acc = 0.f;
    if (isbf) {
        const bf16* w = (const bf16*)fc1w;
        #pragma unroll 8
        for (int k = k0; k < k0 + 64; k++) acc += p[k] * __bfloat162float(w[k * 64 + o]);
    } else {
        const float* w = (const float*)fc1w;
        #pragma unroll 8
        for (int k = k0; k < k0 + 64; k++) acc += p[k] * w[k * 64 + o];
    }
    zpart[q][o] = acc;
    __syncthreads();
    if (t < 64) {
        float v = zpart[0][t] + zpart[1][t] + zpart[2][t] + zpart[3][t] + ldf(fc1b, t, isbf);
        z[t] = v > 0.f ? v : 0.f;
    }
    __syncthreads();
    if (t < NCLS) {
        float a2 = ldf(fc2b, t, isbf);
        #pragma unroll 8
        for (int k = 0; k < 64; k++) a2 += z[k] * ldf(fc2w, k * NCLS + t, isbf);
        logits[t] = a2;
    }
    __syncthreads();
    if (t == 0) {
        float mx = logits[0];
        for (int j = 1; j < NCLS; j++) mx = fmaxf(mx, logits[j]);
        float se = 0.f;
        for (int j = 0; j < NCLS; j++) se += expf(logits[j] - mx);
        lse = mx + logf(se);
    }
    __syncthreads();
    if (t < NCLS) stf(out, g * NCLS + t, logits[t] - lse, isbf);
}

extern "C" void kernel_launch(void* const* d_in, const int* in_sizes, int n_in,
                              void* d_out, int out_size, void* d_ws, size_t ws_size,
                              hipStream_t stream) {
    const void* x = d_in[0];
    const int* edge_index = (const int*)d_in[1];
    const int* batch = (const int*)d_in[2];
    const void* W1 = d_in[3];
    const void* att_src1 = d_in[4];
    const void* att_dst1 = d_in[5];
    const void* b1 = d_in[6];
    const void* gamma1 = d_in[7];
    const void* beta1 = d_in[8];
    const void* W2 = d_in[9];
    const void* att_src2 = d_in[10];
    const void* att_dst2 = d_in[11];
    const void* b2 = d_in[12];
    const void* gamma2 = d_in[13];
    const void* beta2 = d_in[14];
    const void* fc1w = d_in[15];
    const void* fc1b = d_in[16];
    const void* fc2w = d_in[17];
    const void* fc2b = d_in[18];

    const int E = in_sizes[1] / 2;     // 400000
    const int ET = E + NNODES;         // + self-loops
    const int NE = NNODES * NF;
    const int NNH = NNODES * NH;
    const int NB = (NNODES + 255) / 256;
    const int NB1 = (NNODES + 1 + 255) / 256;
    const int NBE = (ET + 255) / 256;  // edge blocks

    // ---- workspace layout ----
    float* ws = (float*)d_ws;
    bf16* aggb = (bf16*)ws;                // N*256 bf16
    float* asrc = ws + NE / 2;             // N*4 (aliases scan scratch early)
    float* adst = asrc + NNH;              // N*4
    int* flags = (int*)(adst + NNH);       // 16
    unsigned char* h8 = (unsigned char*)(flags + 16);  // MPAD*256 fp8
    bf16* l1ob = (bf16*)(h8 + (size_t)MPAD * NF);      // (dead, layout keep)
    int* rowptr = (int*)(l1ob + (size_t)MPAD * NF);    // N+1 (+pad)
    int* srcs = rowptr + NNODES + 16;      // ET
    int* goff = srcs + ET + 16;            // NG+1
    // zero region (single memset): deg, cursor, gcnt, pooled, bnstat
    int* deg = goff + NG + 1 + 14;
    int* cursor = deg + NNODES;
    int* gcnt = cursor + NNODES;
    float* pooled = (float*)(gcnt + NG);   // 64*256
    float* bnstat = pooled + NG * NF;      // 4*256
    size_t zero_bytes = (size_t)(2 * NNODES + NG) * 4 + (size_t)(NG * NF + 4 * NF) * 4;
    short* Bf1 = (short*)(bnstat + 4 * NF);  // 65536 (outside zero region)
    short* Bf2 = Bf1 + NF * NF;              // 65536
    float* scale1 = (float*)(Bf2 + NF * NF); // 256
    float* shift1 = scale1 + NF;             // 256
    // scan scratch aliased onto asrc/adst (overwritten later by gemm epilogue)
    int* eprefix = (int*)asrc;
    int* bsums = eprefix + NNODES + 16;
    int* boffs = bsums + 256;

    float* bnsum1 = bnstat;
    float* bnsq1 = bnstat + NF;
    float* bnsum2 = bnstat + 2 * NF;
    float* bnsq2 = bnstat + 3 * NF;

    detect_kernel<<<1, 256, 0, stream>>>(edge_index, (const unsigned*)W1, flags);
    (void)hipMemsetAsync(deg, 0, zero_bytes, stream);

    // repack W1 + repack W2 + deg histogram, one dispatch
    prep_kernel<<<512 + NBE, 256, 0, stream>>>(W1, Bf1, W2, Bf2, edge_index, deg, E, ET, flags);
    scan1_kernel<<<NB, 256, 0, stream>>>(deg, eprefix, bsums, NNODES);
    scan2_goff_kernel<<<1, 256, 0, stream>>>(bsums, boffs, NB, batch, goff, gcnt, flags);
    scan3_kernel<<<NB1, 256, 0, stream>>>(eprefix, boffs, rowptr, NNODES, ET);

    // ================= layer 1 (gemm fused with edge scatter) ===============
    scatter_gemm1_kernel<<<GEMM_BLKS + NBE, 256, 0, stream>>>(
        edge_index, rowptr, cursor, srcs, E, ET,
        x, Bf1, h8, NNODES, att_src1, att_dst1, asrc, adst, flags);
    agg_csr_kernel<<<NNODES, 64, 0, stream>>>(rowptr, srcs, asrc, adst, h8, b1, x, aggb,
                                              flags, 1, nullptr, nullptr);
    bn_stats_kernel<<<512, 256, 0, stream>>>(aggb, bnsum1, bnsq1);
    bn_finalize_kernel<<<1, 256, 0, stream>>>(bnsum1, bnsq1, gamma1, beta1, scale1, shift1, flags);

    // ================= layer 2 (BN-1 affine via precomputed coefficients) ===
    gemm2_kernel<<<GEMM_BLKS, 256, 0, stream>>>(aggb, Bf2, h8, NNODES,
                                                att_src2, att_dst2, asrc, adst,
                                                scale1, shift1, flags);
    agg_csr_kernel<<<NNODES, 64, 0, stream>>>(rowptr, srcs, asrc, adst, h8, b2, aggb, aggb,
                                              flags, 0, scale1, shift1);

    // ================= stats-2 + pool (fused) + head ========================
    stats_pool_kernel<<<512 + NG * 8, 256, 0, stream>>>(aggb, bnsum2, bnsq2, goff, pooled);
    head_kernel<<<NG, 256, 0, stream>>>(pooled, gcnt, bnsum2, bnsq2, gamma2, beta2,
                                        fc1w, fc1b, fc2w, fc2b, d_out, flags);
}